// Round 10
// baseline (176.948 us; speedup 1.0000x reference)
//
#include <hip/hip_runtime.h>

// Problem constants
#define N_ROWS 131072    // 32*4096
#define D 64
#define K_CODES 1024
#define RPB 128          // rows per block
#define CH_TILES 4       // 16-code tiles per staged chunk (64 codes, 16 KB)
#define NCHUNK 16

typedef _Float16 f16x8 __attribute__((ext_vector_type(8)));
typedef float    f32x4 __attribute__((ext_vector_type(4)));

#define MFMA16(a, b, c) __builtin_amdgcn_mfma_f32_16x16x32_f16((a), (b), (c), 0, 0, 0)

// Direct global->LDS DMA, 16 B per lane. Global addr is per-lane
// (base + lane*16); LDS addr is the wave-uniform base (HW adds lane*16).
#define ASYNC_COPY16(gp, lp)                                                  \
    __builtin_amdgcn_global_load_lds(                                         \
        (const __attribute__((address_space(1))) void*)(gp),                  \
        (__attribute__((address_space(3))) void*)(lp), 16, 0, 0)

// ---------------------------------------------------------------------------
// ws layout: csqr[1024] f32 (4 KB) | CBf: 16384 f16x8 units (256 KB)
// CBf unit index = tile*256 + f*64 + lane, f in {0:hi k0-31, 1:hi k32-63,
// 2:lo k0-31, 3:lo k32-63}; unit holds the 8 halves lane needs for that
// MFMA B fragment: B[k=(lane>>4)*8+j][n=lane&15], code = tile*16 + n.
// This unit order is exactly the order global_load_lds writes LDS (base +
// lane*16), so staged chunks are fragment-addressable with ds_read_b128.
// ---------------------------------------------------------------------------
__global__ __launch_bounds__(256)
void prep_kernel(const float* __restrict__ CB, _Float16* __restrict__ CBf,
                 float* __restrict__ csqr, float* __restrict__ loss) {
    const int b = blockIdx.x, t = threadIdx.x;
    if (b < 64) {
        const int unit = b * 256 + t;
        const int tile = unit >> 8;
        const int f    = (unit >> 6) & 3;
        const int lane = unit & 63;
        const int quad = lane >> 4, lrow = lane & 15;
        const int code = tile * 16 + lrow;
        const int k0   = (f & 1) * 32 + quad * 8;
        const float* src = CB + (size_t)code * D + k0;
        float4 v0 = *(const float4*)(src);
        float4 v1 = *(const float4*)(src + 4);
        float xs[8] = {v0.x, v0.y, v0.z, v0.w, v1.x, v1.y, v1.z, v1.w};
        f16x8 o;
#pragma unroll
        for (int j = 0; j < 8; ++j) {
            _Float16 h = (_Float16)xs[j];
            o[j] = (f < 2) ? h : (_Float16)(xs[j] - (float)h);
        }
        *(f16x8*)(CBf + (size_t)unit * 8) = o;
    } else {
        if (t == 0) *loss = 0.0f;
        for (int k = t; k < K_CODES; k += 256) {
            const float4* p = (const float4*)(CB + (size_t)k * D);
            float s = 0.0f;
#pragma unroll
            for (int i = 0; i < 16; ++i) {
                float4 v = p[i];
                s += v.x * v.x + v.y * v.y + v.z * v.z + v.w * v.w;
            }
            csqr[k] = s;
        }
    }
}

// ---------------------------------------------------------------------------
// K1: m97-style LDS-staged split-f16 MFMA argmin + fused z_q + loss.
// Block = 128 rows, 4 waves; wave w owns rows [R0+w*32, +32) (MT=2) and
// sweeps ALL 1024 codes. B chunks (4 tiles = 64 codes = 16 KB) staged into
// a 2x16KB LDS double buffer via global_load_lds DMA (each wave stages a
// 4 KB quarter); chunk c+1 DMA issues right after the barrier and has the
// full chunk-c compute window to land -> prefetch depth without VGPRs
// (R7/R9 lesson: the scheduler collapses register pipelines).
// score = |c|^2 + (-2x)·c, acc-init = csqr, 6 MFMAs/tile/mt (hh,lh,hl;
// ll ~2^-24 dropped). Codes ascend across chunks -> strict < keeps
// np.argmin first-min. Epilogue: per-wave argmin finalize (no cross-wave
// merge needed), then block-cooperative contiguous zq span write
// (16B-aligned despite out+1).
// ---------------------------------------------------------------------------
__global__ __launch_bounds__(256, 4)
void argmin_kernel(const float* __restrict__ X,
                   const _Float16* __restrict__ CBf,
                   const float* __restrict__ csqr,
                   const float* __restrict__ CB,
                   float* __restrict__ out) {
    __shared__ __align__(16) _Float16 Bs[2][CH_TILES * 256 * 8]; // 2x16 KB
    __shared__ float LsC[K_CODES];                               // 4 KB
    __shared__ int   ivfin[RPB];

    const int t    = threadIdx.x;
    const int wave = t >> 6;
    const int lane = t & 63;
    const int lrow = lane & 15;
    const int quad = lane >> 4;
    const int R0   = blockIdx.x * RPB;
    const int Rw   = R0 + wave * 32;

    // Stage csqr to LDS (drained by the first barrier).
    ((float4*)LsC)[t] = ((const float4*)csqr)[t];

    // ---- A fragments: (-2x) split hi/lo; xsq covers this wave's 32 rows
    // exactly once. A layout: lane holds A[m=lane&15][k=quad*8+j], j=0..7.
    f16x8 Ah[2][2], Al[2][2];
    float xsq = 0.0f;
#pragma unroll
    for (int mt = 0; mt < 2; ++mt) {
        const float* xr = X + (size_t)(Rw + mt * 16 + lrow) * D;
#pragma unroll
        for (int ks = 0; ks < 2; ++ks) {
            const int k0 = ks * 32 + quad * 8;
            float4 v0 = *(const float4*)(xr + k0);
            float4 v1 = *(const float4*)(xr + k0 + 4);
            float xs[8] = {v0.x, v0.y, v0.z, v0.w, v1.x, v1.y, v1.z, v1.w};
            f16x8 h, l;
#pragma unroll
            for (int j = 0; j < 8; ++j) {
                xsq += xs[j] * xs[j];
                float sv = -2.0f * xs[j];
                _Float16 hh = (_Float16)sv;
                h[j] = hh;
                l[j] = (_Float16)(sv - (float)hh);
            }
            Ah[mt][ks] = h;
            Al[mt][ks] = l;
        }
    }

    float bestd[2][4];
    int   besti[2][4];
#pragma unroll
    for (int mt = 0; mt < 2; ++mt)
#pragma unroll
        for (int r = 0; r < 4; ++r) { bestd[mt][r] = 3.0e38f; besti[mt][r] = 0; }

    // Wave stages its 4 KB quarter of each 16 KB chunk.
#define STAGE(c, b)                                                           \
    do {                                                                      \
        const char* gb = (const char*)CBf + (size_t)(c) * 16384               \
                         + wave * 4096 + lane * 16;                           \
        _Float16* lb = &Bs[b][wave * 2048];   /* uniform LDS base */          \
        ASYNC_COPY16(gb,        lb);                                          \
        ASYNC_COPY16(gb + 1024, lb + 512);                                    \
        ASYNC_COPY16(gb + 2048, lb + 1024);                                   \
        ASYNC_COPY16(gb + 3072, lb + 1536);                                   \
    } while (0)

    STAGE(0, 0);
    __syncthreads();   // drains chunk-0 DMA (vmcnt) + LsC stores, all waves

    for (int c = 0; c < NCHUNK; ++c) {
        const int cb = c & 1;
        if (c + 1 < NCHUNK) STAGE(c + 1, (c + 1) & 1);   // issue DMA first

#pragma unroll
        for (int tl = 0; tl < CH_TILES; ++tl) {
            // B frags: contiguous-lane ds_read_b128 (conflict-free).
            const f16x8* bu = (const f16x8*)&Bs[cb][0] + tl * 256 + lane;
            f16x8 Bh0 = bu[0], Bh1 = bu[64], Bl0 = bu[128], Bl1 = bu[192];
            const int   cc = (c * CH_TILES + tl) * 16 + lrow;
            const float cs = LsC[cc];
#pragma unroll
            for (int mt = 0; mt < 2; ++mt) {
                f32x4 acc = {cs, cs, cs, cs};   // score = |c|^2 + (-2x)·c
                acc = MFMA16(Ah[mt][0], Bh0, acc);
                acc = MFMA16(Ah[mt][1], Bh1, acc);
                acc = MFMA16(Al[mt][0], Bh0, acc);
                acc = MFMA16(Al[mt][1], Bh1, acc);
                acc = MFMA16(Ah[mt][0], Bl0, acc);
                acc = MFMA16(Ah[mt][1], Bl1, acc);
#pragma unroll
                for (int r = 0; r < 4; ++r) {
                    bool lt = acc[r] < bestd[mt][r];
                    bestd[mt][r] = lt ? acc[r] : bestd[mt][r];
                    besti[mt][r] = lt ? cc : besti[mt][r];
                }
            }
        }
        __syncthreads();   // readers done with cb; c+1 DMA drained (vmcnt 0)
    }

    const float scale = 1.25f / (float)((size_t)N_ROWS * D);

    // ---- Per-wave finalize: reduce across 16 code-columns (lexicographic
    // on exact ties -> np.argmin first-min), write idxf + ivfin, loss parts.
    float ssum = 0.0f;
#pragma unroll
    for (int mt = 0; mt < 2; ++mt) {
#pragma unroll
        for (int r = 0; r < 4; ++r) {
            float dv = bestd[mt][r];
            int   iv = besti[mt][r];
#pragma unroll
            for (int m = 1; m < 16; m <<= 1) {
                float od = __shfl_xor(dv, m, 64);
                int   oi = __shfl_xor(iv, m, 64);
                if (od < dv || (od == dv && oi < iv)) { dv = od; iv = oi; }
            }
            if (lrow == 0) {
                int rl = wave * 32 + mt * 16 + quad * 4 + r;   // 0..127
                ivfin[rl] = iv;
                out[1 + (size_t)N_ROWS * D + R0 + rl] = (float)iv;   // idxf
                ssum += dv;
            }
        }
    }
    // ssum on lanes 0,16,32,48; fold quads; add wave's xsq; 1 atomic/wave.
    ssum += __shfl_xor(ssum, 16, 64);
    ssum += __shfl_xor(ssum, 32, 64);
#pragma unroll
    for (int m = 1; m < 64; m <<= 1) xsq += __shfl_xor(xsq, m, 64);
    if (lane == 0) atomicAdd(out, (ssum + xsq) * scale);
    __syncthreads();

    // ---- Block-cooperative zq span write: dwords [R0*64, R0*64+8192) at
    // out+1. Global dword offset 1+R0*64+j is 16B-aligned iff j%4==3.
    float* p = out + 1 + (size_t)R0 * D;
#pragma unroll
    for (int i = 0; i < 8; ++i) {
        int q = i * 256 + t;        // 0..2047
        int j = 4 * q + 3;          // 3,7,...,8191
        if (q < 2047) {
            float v[4];
#pragma unroll
            for (int e = 0; e < 4; ++e) {
                int jj = j + e;     // may straddle a row boundary
                v[e] = CB[(size_t)ivfin[jj >> 6] * D + (jj & 63)];
            }
            *(float4*)(p + j) = make_float4(v[0], v[1], v[2], v[3]);
        } else if (q == 2047) {
            p[8191] = CB[(size_t)ivfin[RPB - 1] * D + 63];
        }
    }
    if (t == 0) {   // head dwords j=0..2 (row 0, cols 0..2)
        const float* c0 = CB + (size_t)ivfin[0] * D;
        p[0] = c0[0];
        p[1] = c0[1];
        p[2] = c0[2];
    }
}

// ---------------------------------------------------------------------------
extern "C" void kernel_launch(void* const* d_in, const int* in_sizes, int n_in,
                              void* d_out, int out_size, void* d_ws,
                              size_t ws_size, hipStream_t stream) {
    const float* X  = (const float*)d_in[0];   // inputs  [131072,64]
    const float* CB = (const float*)d_in[1];   // codebook [1024,64]

    float*    csqr = (float*)d_ws;                      // 4 KB
    _Float16* CBf  = (_Float16*)((char*)d_ws + 4096);   // 256 KB

    hipLaunchKernelGGL(prep_kernel, dim3(65), dim3(256), 0, stream,
                       CB, CBf, csqr, (float*)d_out);
    hipLaunchKernelGGL(argmin_kernel, dim3(N_ROWS / RPB), dim3(256), 0, stream,
                       X, CBf, csqr, CB, (float*)d_out);
}